// Round 2
// baseline (30739.090 us; speedup 1.0000x reference)
//
#include <hip/hip_runtime.h>
#include <hip/hip_bf16.h>
#include <math.h>

#define BB 512
#define HH 512
#define TT 1024

typedef __bf16 bf16;
typedef __bf16 bf16x8 __attribute__((ext_vector_type(8)));
typedef float f32x4 __attribute__((ext_vector_type(4)));

// ---------------- ws layout (bytes) ----------------
// Wt   : [2048][512] bf16  @ 0       (2 MB)   row = gate-col (i,f,g,o blocked), col = k
// bias : [2048] f32        @ 2 MB    (8 KB)   b_ih + b_hh
// hb0  : [512][512] bf16   @ +8 KB   (512 KB)
// hb1  : next              (512 KB)
// flags: [16*32] int       @ next    (2 KB)   one counter per bt, 128B-spaced
#define WT_OFF    0
#define B0_OFF    (2*1024*1024)
#define H0_OFF    (B0_OFF + 8192)
#define H1_OFF    (H0_OFF + 512*1024)
#define FL_OFF    (H1_OFF + 512*1024)

__global__ void prep_weights(const float* __restrict__ Whh,
                             const float* __restrict__ bih, const float* __restrict__ bhh,
                             bf16* __restrict__ Wt, float* __restrict__ bias) {
    int col = blockIdx.x;                 // 0..2047
    for (int k = threadIdx.x; k < HH; k += blockDim.x)
        Wt[col * HH + k] = (bf16)Whh[col * HH + k];
    if (threadIdx.x == 0) bias[col] = bih[col] + bhh[col];
}

__global__ void prep_state(const float* __restrict__ h,
                           bf16* __restrict__ h0buf, int* __restrict__ flags) {
    int i = blockIdx.x * blockDim.x + threadIdx.x;
    if (i < BB * HH) h0buf[i] = (bf16)h[i];
    if (blockIdx.x == 0)
        for (int j = threadIdx.x; j < 16 * 32; j += blockDim.x) flags[j] = 0;
}

__device__ __forceinline__ float tanh_fast(float x) {
    float ax = fabsf(x);
    float e = __expf(-2.f * ax);
    float r = (1.f - e) / (1.f + e);
    return copysignf(r, x);
}
__device__ __forceinline__ float sigmoid_fast(float x) {
    return 1.f / (1.f + __expf(-x));
}

// Persistent LSTM. grid = 256 wgs x 256 thr (4 waves). wg (bt,hs): batch rows
// bt*32..+32, hidden cols hs*32..+32 (all 4 gates). Wave w owns hidden cols
// w*8..w*8+8 within the slice; B-rows per wave = {gate 0..3} x {8 cols} = 32.
// Weights live in VGPRs for all 1024 steps. Sync: per-bt release/acquire
// counter (16 producers). Deadlock-safe: launch_bounds(256,2) => <=256 VGPR
// => 2 wgs/CU capacity => all 256 wgs resident under any placement.
__global__ __launch_bounds__(256, 2) void lstm_persist(
    const bf16* __restrict__ Wt,      // [2048][512] bf16
    const float* __restrict__ bias,   // [2048]
    const float* __restrict__ Wih,    // [2048]
    const float* __restrict__ Wfc,    // [512]
    const float* __restrict__ bfc,    // [1]
    const float* __restrict__ c0,     // [512*512] f32
    bf16* __restrict__ hb0,
    bf16* __restrict__ hb1,
    int* __restrict__ flags,          // [16*32]
    float* __restrict__ out)          // [512][1024]
{
    __shared__ __align__(16) bf16 Alds[32 * 512];  // XOR-swizzled h tile (32 KB)
    __shared__ float xls[32];                      // x_s for our 32 batch rows
    __shared__ float WfcLDS[512];

    const int tid  = threadIdx.x;
    const int wave = tid >> 6;
    const int lane = tid & 63;
    const int l15  = lane & 15;
    const int hi   = lane >> 4;
    // XCD swizzle: presumed XCD = blockIdx%8; co-locate each bt-group (16 wgs)
    // on one XCD so the per-step h exchange stays in local L2. Perf-only.
    const int xcd = blockIdx.x & 7;
    const int ii  = blockIdx.x >> 3;          // 0..31
    const int bt  = xcd * 2 + (ii & 1);       // 0..15
    const int hs  = ii >> 1;                  // 0..15

    // ---- one-time: Wfc -> LDS ----
    WfcLDS[tid] = Wfc[tid];
    WfcLDS[tid + 256] = Wfc[tid + 256];

    // ---- preload weights into registers ----
    // lane's B-row for tile nt (0: gates i,f ; 1: gates g,o):
    //   gate = nt*2 + (l15>>3), col j = hs*32 + wave*8 + (l15&7)
    bf16x8 breg[2][16];
    float biasr[2], wihr[2];
    #pragma unroll
    for (int nt = 0; nt < 2; ++nt) {
        int gcol = (nt * 2 + (l15 >> 3)) * HH + hs * 32 + wave * 8 + (l15 & 7);
        const bf16* wp = Wt + (size_t)gcol * HH + hi * 8;
        #pragma unroll
        for (int kk = 0; kk < 16; ++kk)
            breg[nt][kk] = *(const bf16x8*)(wp + kk * 32);
        biasr[nt] = bias[gcol];
        wihr[nt]  = Wih[gcol];
    }
    const bool lo = (l15 < 8);
    float p0 = __shfl_xor(biasr[0], 8), p1 = __shfl_xor(biasr[1], 8);
    const float bI = lo ? biasr[0] : p0, bF = lo ? p0 : biasr[0];
    const float bG = lo ? biasr[1] : p1, bO = lo ? p1 : biasr[1];
    p0 = __shfl_xor(wihr[0], 8); p1 = __shfl_xor(wihr[1], 8);
    const float wI = lo ? wihr[0] : p0, wF = lo ? p0 : wihr[0];
    const float wG = lo ? wihr[1] : p1, wO = lo ? p1 : wihr[1];

    // ---- c-state in registers: lane owns rows mymt*16+hi*4+r (r=0..3), col jloc
    const int mymt = lo ? 0 : 1;
    const int jloc = hs * 32 + wave * 8 + (l15 & 7);
    float creg[4];
    #pragma unroll
    for (int r = 0; r < 4; ++r) {
        int brow = bt * 32 + mymt * 16 + hi * 4 + r;
        creg[r] = c0[(size_t)brow * HH + jloc];
    }
    const float bfcv = bfc[0];

    int* myflag = flags + bt * 32;
    const int swz = l15 & 7;

    __syncthreads();   // WfcLDS ready

    for (int s = 0; s < TT; ++s) {
        const bf16* hin  = (s & 1) ? hb1 : hb0;
        bf16*       hout = (s & 1) ? hb0 : hb1;

        // 1. wait for all 16 producers of our bt-group to finish step s-1
        if (lane == 0) {
            while (__hip_atomic_load(myflag, __ATOMIC_ACQUIRE,
                                     __HIP_MEMORY_SCOPE_AGENT) < 16 * s)
                __builtin_amdgcn_s_sleep(1);
        }

        // 2. stage h_s tile [32 x 512] into swizzled LDS
        {
            int row = tid >> 3, r7 = row & 7;
            int cseg = (tid & 7) * 8;                  // first chunk (8 bf16 each)
            const bf16* src = hin + (((size_t)(bt * 32 + row)) << 9) + (tid & 7) * 64;
            bf16* drow = Alds + row * 512;
            #pragma unroll
            for (int u = 0; u < 8; ++u)
                *(bf16x8*)(drow + (((cseg + u) ^ r7) << 3)) = *(const bf16x8*)(src + u * 8);
        }
        __syncthreads();

        // 3. x_s = FC(h_s) per batch row (all wgs; hs==0 also emits y[:, s-1])
        {
            int row = tid >> 3, seg = tid & 7, r7 = row & 7;
            float xacc = 0.f;
            if (s > 0) {
                const bf16* arow = Alds + row * 512;
                #pragma unroll
                for (int u = 0; u < 8; ++u) {
                    int cc = seg * 8 + u;
                    bf16x8 v = *(const bf16x8*)(arow + ((cc ^ r7) << 3));
                    const float* wv = WfcLDS + cc * 8;
                    #pragma unroll
                    for (int e = 0; e < 8; ++e) xacc += (float)v[e] * wv[e];
                }
                xacc += __shfl_xor(xacc, 1);
                xacc += __shfl_xor(xacc, 2);
                xacc += __shfl_xor(xacc, 4);
                xacc += bfcv;
            }
            if (seg == 0) {
                xls[row] = xacc;                       // x_0 = 0
                if (hs == 0 && s > 0)
                    out[((size_t)(bt * 32 + row)) * TT + (s - 1)] = xacc;
            }
        }

        // 4. MFMA: [32,512] @ [512, 32 B-rows] ; A from swizzled LDS, B from regs
        f32x4 acc[2][2];
        #pragma unroll
        for (int i = 0; i < 2; ++i)
            #pragma unroll
            for (int j = 0; j < 2; ++j) acc[i][j] = (f32x4)0.f;

        #pragma unroll
        for (int kk = 0; kk < 16; ++kk) {
            int ch = ((hi + 4 * kk) ^ swz) << 3;
            bf16x8 a0 = *(const bf16x8*)(Alds + l15 * 512 + ch);
            bf16x8 a1 = *(const bf16x8*)(Alds + (l15 + 16) * 512 + ch);
            acc[0][0] = __builtin_amdgcn_mfma_f32_16x16x32_bf16(a0, breg[0][kk], acc[0][0], 0, 0, 0);
            acc[0][1] = __builtin_amdgcn_mfma_f32_16x16x32_bf16(a0, breg[1][kk], acc[0][1], 0, 0, 0);
            acc[1][0] = __builtin_amdgcn_mfma_f32_16x16x32_bf16(a1, breg[0][kk], acc[1][0], 0, 0, 0);
            acc[1][1] = __builtin_amdgcn_mfma_f32_16x16x32_bf16(a1, breg[1][kk], acc[1][1], 0, 0, 0);
        }
        __syncthreads();   // xls ready (written pre-MFMA), Alds reads done

        // 5. pointwise: lane handles rows mymt*16+hi*4+r, col jloc.
        //    One shfl_xor(8) per (nt,r) swaps the i<->f / g<->o halves.
        #pragma unroll
        for (int r = 0; r < 4; ++r) {
            float send0 = lo ? acc[1][0][r] : acc[0][0][r];
            float send1 = lo ? acc[1][1][r] : acc[0][1][r];
            float recv0 = __shfl_xor(send0, 8);
            float recv1 = __shfl_xor(send1, 8);
            float own0  = lo ? acc[0][0][r] : acc[1][0][r];
            float own1  = lo ? acc[0][1][r] : acc[1][1][r];
            int  lrow = mymt * 16 + hi * 4 + r;
            float xsv = xls[lrow];
            float xi = (lo ? own0 : recv0) + bI + xsv * wI;
            float xf = (lo ? recv0 : own0) + bF + xsv * wF;
            float xg = (lo ? own1 : recv1) + bG + xsv * wG;
            float xo = (lo ? recv1 : own1) + bO + xsv * wO;
            float si = sigmoid_fast(xi), sf = sigmoid_fast(xf), so = sigmoid_fast(xo);
            float tg = tanh_fast(xg);
            float cn = sf * creg[r] + si * tg;
            creg[r] = cn;
            float hn = so * tanh_fast(cn);
            hout[(size_t)(bt * 32 + lrow) * HH + jloc] = (bf16)hn;
        }
        __syncthreads();   // all h stores issued+drained (barrier drains vmcnt)

        // 6. publish
        if (tid == 0)
            __hip_atomic_fetch_add(myflag, 1, __ATOMIC_RELEASE, __HIP_MEMORY_SCOPE_AGENT);
    }

    // ---- final output column: y[:, TT-1] = FC(h_TT) ----
    if (hs == 0) {
        if (lane == 0) {
            while (__hip_atomic_load(myflag, __ATOMIC_ACQUIRE,
                                     __HIP_MEMORY_SCOPE_AGENT) < 16 * TT)
                __builtin_amdgcn_s_sleep(1);
        }
        __syncthreads();
        int row = tid >> 3, seg = tid & 7;
        const bf16* hrow = ((TT & 1) ? hb1 : hb0) + (size_t)(bt * 32 + row) * HH + seg * 64;
        float xacc = 0.f;
        #pragma unroll
        for (int u = 0; u < 8; ++u) {
            bf16x8 v = *(const bf16x8*)(hrow + u * 8);
            const float* wv = WfcLDS + seg * 64 + u * 8;
            #pragma unroll
            for (int e = 0; e < 8; ++e) xacc += (float)v[e] * wv[e];
        }
        xacc += __shfl_xor(xacc, 1);
        xacc += __shfl_xor(xacc, 2);
        xacc += __shfl_xor(xacc, 4);
        if (seg == 0)
            out[(size_t)(bt * 32 + row) * TT + (TT - 1)] = xacc + bfcv;
    }
}

extern "C" void kernel_launch(void* const* d_in, const int* in_sizes, int n_in,
                              void* d_out, int out_size, void* d_ws, size_t ws_size,
                              hipStream_t stream) {
    const float* h   = (const float*)d_in[0];
    const float* c   = (const float*)d_in[1];
    const float* Wih = (const float*)d_in[2];
    const float* Whh = (const float*)d_in[3];
    const float* bih = (const float*)d_in[4];
    const float* bhh = (const float*)d_in[5];
    const float* Wfc = (const float*)d_in[6];
    const float* bfc = (const float*)d_in[7];
    float* out = (float*)d_out;

    char* ws = (char*)d_ws;
    bf16*  Wt    = (bf16*)(ws + WT_OFF);
    float* bias  = (float*)(ws + B0_OFF);
    bf16*  hb0   = (bf16*)(ws + H0_OFF);
    bf16*  hb1   = (bf16*)(ws + H1_OFF);
    int*   flags = (int*)(ws + FL_OFF);

    prep_weights<<<2048, 256, 0, stream>>>(Whh, bih, bhh, Wt, bias);
    prep_state<<<1024, 256, 0, stream>>>(h, hb0, flags);
    lstm_persist<<<256, 256, 0, stream>>>(Wt, bias, Wih, Wfc, bfc, c,
                                          hb0, hb1, flags, out);
}

// Round 3
// 11843.019 us; speedup vs baseline: 2.5955x; 2.5955x over previous
//
#include <hip/hip_runtime.h>
#include <hip/hip_bf16.h>
#include <math.h>

#define BB 512
#define HH 512
#define TT 1024

typedef __bf16 bf16;
typedef __bf16 bf16x8 __attribute__((ext_vector_type(8)));
typedef __bf16 bf16x4v __attribute__((ext_vector_type(4)));
typedef float f32x4 __attribute__((ext_vector_type(4)));
typedef unsigned long long ull;

// ---------------- ws layout (bytes) ----------------
// WcT  : [2048][512] bf16  @ 0       (2 MB)   folded: Whh + Wfc ⊗ Wih
// biasC: [2048] f32        @ 2 MB    (8 KB)   b_ih + b_hh + bfc*Wih
// hb0  : [512][512] bf16   @ +8 KB   (512 KB)
// hb1  : next              (512 KB)
// flags: [16*32] int       @ next    (2 KB)
#define WT_OFF    0
#define BC_OFF    (2*1024*1024)
#define H0_OFF    (BC_OFF + 8192)
#define H1_OFF    (H0_OFF + 512*1024)
#define FL_OFF    (H1_OFF + 512*1024)

__global__ void prep_weights(const float* __restrict__ Whh, const float* __restrict__ Wih,
                             const float* __restrict__ bih, const float* __restrict__ bhh,
                             const float* __restrict__ Wfc, const float* __restrict__ bfc,
                             bf16* __restrict__ WcT, float* __restrict__ biasC) {
    int col = blockIdx.x;                 // 0..2047
    float wih = Wih[col];
    for (int k = threadIdx.x; k < HH; k += blockDim.x)
        WcT[col * HH + k] = (bf16)(Whh[col * HH + k] + Wfc[k] * wih);
    if (threadIdx.x == 0) biasC[col] = bih[col] + bhh[col] + bfc[0] * wih;
}

__global__ void prep_state(const float* __restrict__ h,
                           bf16* __restrict__ h0buf, int* __restrict__ flags) {
    int i = blockIdx.x * blockDim.x + threadIdx.x;
    if (i < BB * HH) h0buf[i] = (bf16)h[i];
    if (blockIdx.x == 0)
        for (int j = threadIdx.x; j < 16 * 32; j += blockDim.x) flags[j] = 0;
}

__device__ __forceinline__ float tanh_fast(float x) {
    float ax = fabsf(x);
    float e = __expf(-2.f * ax);
    float r = (1.f - e) / (1.f + e);
    return copysignf(r, x);
}
__device__ __forceinline__ float sigmoid_fast(float x) {
    return 1.f / (1.f + __expf(-x));
}

// Persistent LSTM, folded-FC weights in VGPRs, h-exchange through L3 (MALL)
// via RELAXED system-scope atomics (sc0 sc1 -> bypass L1/L2, device-coherent,
// placement-independent). No acquire/release cache maintenance in the loop
// except the per-step RELEASE bump (wbl2 on a clean L2).
__global__ __launch_bounds__(256, 1) void lstm_persist(
    const bf16* __restrict__ WcT,     // [2048][512] bf16 (folded)
    const float* __restrict__ biasC,  // [2048]
    const float* __restrict__ Wih,    // [2048]
    const float* __restrict__ Wfc,    // [512]
    const float* __restrict__ bfc,    // [1]
    const float* __restrict__ c0,     // [512*512] f32
    bf16* __restrict__ hb0,
    bf16* __restrict__ hb1,
    int* __restrict__ flags,          // [16*32]
    float* __restrict__ out)          // [512][1024]
{
    __shared__ __align__(16) bf16 Alds[32 * 512];  // XOR-swizzled h tile (32 KB)
    __shared__ float xls[32];                      // step-0 correction per row
    __shared__ float WfcLDS[512];
    __shared__ bf16 hrep[32][40];                  // h repack for coalesced stores

    const int tid  = threadIdx.x;
    const int wave = tid >> 6;
    const int lane = tid & 63;
    const int l15  = lane & 15;
    const int hi   = lane >> 4;
    // group mapping (XCD swizzle is perf-only; correctness is placement-free)
    const int xcd = blockIdx.x & 7;
    const int ii  = blockIdx.x >> 3;
    const int bt  = xcd * 2 + (ii & 1);       // 0..15
    const int hs  = ii >> 1;                  // 0..15

    WfcLDS[tid] = Wfc[tid];
    WfcLDS[tid + 256] = Wfc[tid + 256];

    // ---- preload folded weights into registers ----
    bf16x8 breg[2][16];
    float biasr[2], wihr[2];
    #pragma unroll
    for (int nt = 0; nt < 2; ++nt) {
        int gcol = (nt * 2 + (l15 >> 3)) * HH + hs * 32 + wave * 8 + (l15 & 7);
        const bf16* wp = WcT + (size_t)gcol * HH + hi * 8;
        #pragma unroll
        for (int kk = 0; kk < 16; ++kk)
            breg[nt][kk] = *(const bf16x8*)(wp + kk * 32);
        biasr[nt] = biasC[gcol];
        wihr[nt]  = Wih[gcol];
    }
    const bool lo = (l15 < 8);
    float p0 = __shfl_xor(biasr[0], 8), p1 = __shfl_xor(biasr[1], 8);
    const float bI = lo ? biasr[0] : p0, bF = lo ? p0 : biasr[0];
    const float bG = lo ? biasr[1] : p1, bO = lo ? p1 : biasr[1];
    p0 = __shfl_xor(wihr[0], 8); p1 = __shfl_xor(wihr[1], 8);
    const float wI = lo ? wihr[0] : p0, wF = lo ? p0 : wihr[0];
    const float wG = lo ? wihr[1] : p1, wO = lo ? p1 : wihr[1];

    const int mymt = lo ? 0 : 1;
    const int jcol = wave * 8 + (l15 & 7);    // col within slice (0..31)
    const int jloc = hs * 32 + jcol;
    float creg[4];
    #pragma unroll
    for (int r = 0; r < 4; ++r) {
        int brow = bt * 32 + mymt * 16 + hi * 4 + r;
        creg[r] = c0[(size_t)brow * HH + jloc];
    }
    const float bfcv = bfc[0];

    int* myflag = flags + bt * 32;
    const int swz = l15 & 7;
    const int row = tid >> 3;                 // staging row 0..31
    const int seg = tid & 7;
    const int r7  = row & 7;
    const ull* srcq0 = (const ull*)hb0 + ((size_t)(bt * 32 + row)) * 128;
    const ull* srcq1 = (const ull*)hb1 + ((size_t)(bt * 32 + row)) * 128;
    ull* dstq0 = (ull*)hb0 + ((size_t)(bt * 32 + row)) * 128 + hs * 8 + seg;
    ull* dstq1 = (ull*)hb1 + ((size_t)(bt * 32 + row)) * 128 + hs * 8 + seg;

    __syncthreads();   // WfcLDS ready

    for (int s = 0; s < TT; ++s) {
        const ull* srcq = (s & 1) ? srcq1 : srcq0;
        ull*       dstq = (s & 1) ? dstq0 : dstq1;

        // 1. wait for all 16 producers of our bt-group (relaxed L3 poll)
        if (lane == 0) {
            while (__hip_atomic_load(myflag, __ATOMIC_RELAXED,
                                     __HIP_MEMORY_SCOPE_SYSTEM) < 16 * s)
                __builtin_amdgcn_s_sleep(1);
        }

        // 2. stage h_s tile [32 x 512] via L3 (sc0 sc1 loads), swizzled LDS
        {
            ull hv[16];
            #pragma unroll
            for (int u = 0; u < 8; ++u) {
                int c = seg * 8 + u;
                hv[2*u]   = __hip_atomic_load((ull*)(srcq + 2*c),     __ATOMIC_RELAXED, __HIP_MEMORY_SCOPE_SYSTEM);
                hv[2*u+1] = __hip_atomic_load((ull*)(srcq + 2*c + 1), __ATOMIC_RELAXED, __HIP_MEMORY_SCOPE_SYSTEM);
            }
            #pragma unroll
            for (int u = 0; u < 8; ++u) {
                int c = seg * 8 + u;
                ull* dst = (ull*)(Alds + row * 512 + ((c ^ r7) << 3));
                dst[0] = hv[2*u];
                dst[1] = hv[2*u+1];
            }
        }
        __syncthreads();

        // 3. FC: step-0 correction (all wgs) and/or y-output (hs==0)
        if (s == 0 || hs == 0) {
            float xacc = 0.f;
            const bf16* arow = Alds + row * 512;
            #pragma unroll
            for (int u = 0; u < 8; ++u) {
                int cc = seg * 8 + u;
                bf16x8 v = *(const bf16x8*)(arow + ((cc ^ r7) << 3));
                const float* wv = WfcLDS + cc * 8;
                #pragma unroll
                for (int e = 0; e < 8; ++e) xacc += (float)v[e] * wv[e];
            }
            xacc += __shfl_xor(xacc, 1);
            xacc += __shfl_xor(xacc, 2);
            xacc += __shfl_xor(xacc, 4);
            xacc += bfcv;
            if (seg == 0) {
                xls[row] = xacc;
                if (hs == 0 && s > 0)
                    __hip_atomic_store(&out[((size_t)(bt * 32 + row)) * TT + (s - 1)],
                                       xacc, __ATOMIC_RELAXED, __HIP_MEMORY_SCOPE_SYSTEM);
            }
        }

        // 4. MFMA: [32,512] @ [512, 32 B-rows]; A from swizzled LDS, B from regs
        f32x4 acc[2][2];
        #pragma unroll
        for (int i = 0; i < 2; ++i)
            #pragma unroll
            for (int j = 0; j < 2; ++j) acc[i][j] = (f32x4)0.f;

        #pragma unroll
        for (int kk = 0; kk < 16; ++kk) {
            int ch = ((hi + 4 * kk) ^ swz) << 3;
            bf16x8 a0 = *(const bf16x8*)(Alds + l15 * 512 + ch);
            bf16x8 a1 = *(const bf16x8*)(Alds + (l15 + 16) * 512 + ch);
            acc[0][0] = __builtin_amdgcn_mfma_f32_16x16x32_bf16(a0, breg[0][kk], acc[0][0], 0, 0, 0);
            acc[0][1] = __builtin_amdgcn_mfma_f32_16x16x32_bf16(a0, breg[1][kk], acc[0][1], 0, 0, 0);
            acc[1][0] = __builtin_amdgcn_mfma_f32_16x16x32_bf16(a1, breg[0][kk], acc[1][0], 0, 0, 0);
            acc[1][1] = __builtin_amdgcn_mfma_f32_16x16x32_bf16(a1, breg[1][kk], acc[1][1], 0, 0, 0);
        }

        if (s == 0) __syncthreads();   // xls visible for the correction

        // 5. pointwise cell update; folded weights already include x-feedback
        //    (s==0: subtract x0c*Wih correction since x_0 = 0)
        #pragma unroll
        for (int r = 0; r < 4; ++r) {
            float send0 = lo ? acc[1][0][r] : acc[0][0][r];
            float send1 = lo ? acc[1][1][r] : acc[0][1][r];
            float recv0 = __shfl_xor(send0, 8);
            float recv1 = __shfl_xor(send1, 8);
            float own0  = lo ? acc[0][0][r] : acc[1][0][r];
            float own1  = lo ? acc[0][1][r] : acc[1][1][r];
            int  lrow = mymt * 16 + hi * 4 + r;
            float xc = (s == 0) ? xls[lrow] : 0.f;
            float xi = (lo ? own0 : recv0) + bI - xc * wI;
            float xf = (lo ? recv0 : own0) + bF - xc * wF;
            float xg = (lo ? own1 : recv1) + bG - xc * wG;
            float xo = (lo ? recv1 : own1) + bO - xc * wO;
            float si = sigmoid_fast(xi), sf = sigmoid_fast(xf), so = sigmoid_fast(xo);
            float tg = tanh_fast(xg);
            float cn = sf * creg[r] + si * tg;
            creg[r] = cn;
            hrep[lrow][jcol] = (bf16)(so * tanh_fast(cn));
        }
        __syncthreads();   // hrep ready; Alds reads finished

        // 6. coalesced h store through L3 (sc0 sc1)
        {
            ull val = *(const ull*)&hrep[row][seg * 4];
            __hip_atomic_store(dstq, val, __ATOMIC_RELAXED, __HIP_MEMORY_SCOPE_SYSTEM);
        }
        __syncthreads();   // every thread's store drained (vmcnt0 at barrier)

        // 7. publish
        if (tid == 0)
            __hip_atomic_fetch_add(myflag, 1, __ATOMIC_RELEASE, __HIP_MEMORY_SCOPE_SYSTEM);
    }

    // ---- final output column: y[:, TT-1] = FC(h_TT) ----
    if (hs == 0) {
        if (lane == 0) {
            while (__hip_atomic_load(myflag, __ATOMIC_RELAXED,
                                     __HIP_MEMORY_SCOPE_SYSTEM) < 16 * TT)
                __builtin_amdgcn_s_sleep(1);
        }
        const ull* src = (TT & 1) ? srcq1 : srcq0;
        float xacc = 0.f;
        #pragma unroll
        for (int u = 0; u < 8; ++u) {
            int c = seg * 8 + u;
            ull q0 = __hip_atomic_load((ull*)(src + 2*c),     __ATOMIC_RELAXED, __HIP_MEMORY_SCOPE_SYSTEM);
            ull q1 = __hip_atomic_load((ull*)(src + 2*c + 1), __ATOMIC_RELAXED, __HIP_MEMORY_SCOPE_SYSTEM);
            bf16x4v v0 = __builtin_bit_cast(bf16x4v, q0);
            bf16x4v v1 = __builtin_bit_cast(bf16x4v, q1);
            const float* wv = WfcLDS + c * 8;
            #pragma unroll
            for (int e = 0; e < 4; ++e) xacc += (float)v0[e] * wv[e];
            #pragma unroll
            for (int e = 0; e < 4; ++e) xacc += (float)v1[e] * wv[4 + e];
        }
        xacc += __shfl_xor(xacc, 1);
        xacc += __shfl_xor(xacc, 2);
        xacc += __shfl_xor(xacc, 4);
        if (seg == 0)
            __hip_atomic_store(&out[((size_t)(bt * 32 + row)) * TT + (TT - 1)],
                               xacc + bfcv, __ATOMIC_RELAXED, __HIP_MEMORY_SCOPE_SYSTEM);
    }
}

extern "C" void kernel_launch(void* const* d_in, const int* in_sizes, int n_in,
                              void* d_out, int out_size, void* d_ws, size_t ws_size,
                              hipStream_t stream) {
    const float* h   = (const float*)d_in[0];
    const float* c   = (const float*)d_in[1];
    const float* Wih = (const float*)d_in[2];
    const float* Whh = (const float*)d_in[3];
    const float* bih = (const float*)d_in[4];
    const float* bhh = (const float*)d_in[5];
    const float* Wfc = (const float*)d_in[6];
    const float* bfc = (const float*)d_in[7];
    float* out = (float*)d_out;

    char* ws = (char*)d_ws;
    bf16*  WcT   = (bf16*)(ws + WT_OFF);
    float* biasC = (float*)(ws + BC_OFF);
    bf16*  hb0   = (bf16*)(ws + H0_OFF);
    bf16*  hb1   = (bf16*)(ws + H1_OFF);
    int*   flags = (int*)(ws + FL_OFF);

    prep_weights<<<2048, 256, 0, stream>>>(Whh, Wih, bih, bhh, Wfc, bfc, WcT, biasC);
    prep_state<<<1024, 256, 0, stream>>>(h, hb0, flags);
    lstm_persist<<<256, 256, 0, stream>>>(WcT, biasC, Wih, Wfc, bfc, c,
                                          hb0, hb1, flags, out);
}

// Round 4
// 7667.997 us; speedup vs baseline: 4.0088x; 1.5445x over previous
//
#include <hip/hip_runtime.h>
#include <hip/hip_bf16.h>
#include <math.h>

#define BB 512
#define HH 512
#define TT 1024

typedef __bf16 bf16;
typedef __bf16 bf16x8 __attribute__((ext_vector_type(8)));
typedef __bf16 bf16x4v __attribute__((ext_vector_type(4)));
typedef float f32x4 __attribute__((ext_vector_type(4)));
typedef unsigned long long ull;

// ---------------- ws layout (bytes) ----------------
// WcT  : [2048][512] bf16  @ 0       (2 MB)   folded: Whh + Wfc ⊗ Wih
// biasC: [2048] f32        @ 2 MB    (8 KB)   b_ih + b_hh + bfc*Wih
// hb0  : [512][512] bf16   @ +8 KB   (512 KB)
// hb1  : next              (512 KB)
// flags: [16*32] int       @ next    (2 KB)   per-producer epoch slots, 128B/bt
#define WT_OFF    0
#define BC_OFF    (2*1024*1024)
#define H0_OFF    (BC_OFF + 8192)
#define H1_OFF    (H0_OFF + 512*1024)
#define FL_OFF    (H1_OFF + 512*1024)

__global__ void prep_weights(const float* __restrict__ Whh, const float* __restrict__ Wih,
                             const float* __restrict__ bih, const float* __restrict__ bhh,
                             const float* __restrict__ Wfc, const float* __restrict__ bfc,
                             bf16* __restrict__ WcT, float* __restrict__ biasC) {
    int col = blockIdx.x;                 // 0..2047
    float wih = Wih[col];
    for (int k = threadIdx.x; k < HH; k += blockDim.x)
        WcT[col * HH + k] = (bf16)(Whh[col * HH + k] + Wfc[k] * wih);
    if (threadIdx.x == 0) biasC[col] = bih[col] + bhh[col] + bfc[0] * wih;
}

__global__ void prep_state(const float* __restrict__ h,
                           bf16* __restrict__ h0buf, int* __restrict__ flags) {
    int i = blockIdx.x * blockDim.x + threadIdx.x;
    if (i < BB * HH) h0buf[i] = (bf16)h[i];
    if (blockIdx.x == 0)
        for (int j = threadIdx.x; j < 16 * 32; j += blockDim.x) flags[j] = 0;
}

__device__ __forceinline__ float tanh_fast(float x) {
    float ax = fabsf(x);
    float e = __expf(-2.f * ax);
    float r = (1.f - e) / (1.f + e);
    return copysignf(r, x);
}
__device__ __forceinline__ float sigmoid_fast(float x) {
    return 1.f / (1.f + __expf(-x));
}

// Persistent LSTM, folded-FC weights in VGPRs, h-exchange through MALL via
// RELAXED system-scope accesses (sc0 sc1: bypass L1/L2, device-coherent,
// placement-independent). NO acquire/release/RMW anywhere in the loop ->
// zero buffer_inv / buffer_wbl2 cache-maintenance ops. Ordering of h-stores
// before the flag store comes from the __syncthreads() vmcnt(0) drain
// (write-through stores are at the coherence point when vmcnt retires).
__global__ __launch_bounds__(256, 1) void lstm_persist(
    const bf16* __restrict__ WcT,     // [2048][512] bf16 (folded)
    const float* __restrict__ biasC,  // [2048]
    const float* __restrict__ Wih,    // [2048]
    const float* __restrict__ Wfc,    // [512]
    const float* __restrict__ bfc,    // [1]
    const float* __restrict__ c0,     // [512*512] f32
    bf16* __restrict__ hb0,
    bf16* __restrict__ hb1,
    int* __restrict__ flags,          // [16*32]
    float* __restrict__ out)          // [512][1024]
{
    __shared__ __align__(16) bf16 Alds[32 * 512];  // XOR-swizzled h tile (32 KB)
    __shared__ float xls[32];                      // step-0 correction per row
    __shared__ float WfcLDS[512];
    __shared__ bf16 hrep[32][40];                  // h repack for coalesced stores

    const int tid  = threadIdx.x;
    const int wave = tid >> 6;
    const int lane = tid & 63;
    const int l15  = lane & 15;
    const int hi   = lane >> 4;
    // group mapping (XCD swizzle is perf-only; correctness is placement-free)
    const int xcd = blockIdx.x & 7;
    const int ii  = blockIdx.x >> 3;
    const int bt  = xcd * 2 + (ii & 1);       // 0..15
    const int hs  = ii >> 1;                  // 0..15

    WfcLDS[tid] = Wfc[tid];
    WfcLDS[tid + 256] = Wfc[tid + 256];

    // ---- preload folded weights into registers ----
    bf16x8 breg[2][16];
    float biasr[2], wihr[2];
    #pragma unroll
    for (int nt = 0; nt < 2; ++nt) {
        int gcol = (nt * 2 + (l15 >> 3)) * HH + hs * 32 + wave * 8 + (l15 & 7);
        const bf16* wp = WcT + (size_t)gcol * HH + hi * 8;
        #pragma unroll
        for (int kk = 0; kk < 16; ++kk)
            breg[nt][kk] = *(const bf16x8*)(wp + kk * 32);
        biasr[nt] = biasC[gcol];
        wihr[nt]  = Wih[gcol];
    }
    const bool lo = (l15 < 8);
    float p0 = __shfl_xor(biasr[0], 8), p1 = __shfl_xor(biasr[1], 8);
    const float bI = lo ? biasr[0] : p0, bF = lo ? p0 : biasr[0];
    const float bG = lo ? biasr[1] : p1, bO = lo ? p1 : biasr[1];
    p0 = __shfl_xor(wihr[0], 8); p1 = __shfl_xor(wihr[1], 8);
    const float wI = lo ? wihr[0] : p0, wF = lo ? p0 : wihr[0];
    const float wG = lo ? wihr[1] : p1, wO = lo ? p1 : wihr[1];

    const int mymt = lo ? 0 : 1;
    const int jcol = wave * 8 + (l15 & 7);    // col within slice (0..31)
    const int jloc = hs * 32 + jcol;
    float creg[4];
    #pragma unroll
    for (int r = 0; r < 4; ++r) {
        int brow = bt * 32 + mymt * 16 + hi * 4 + r;
        creg[r] = c0[(size_t)brow * HH + jloc];
    }
    const float bfcv = bfc[0];

    int* myslots = flags + bt * 32;           // 16 producer slots for our bt
    int* myslot  = myslots + hs;              // our own slot
    const int swz = l15 & 7;
    const int row = tid >> 3;                 // staging row 0..31
    const int seg = tid & 7;
    const int r7  = row & 7;
    const ull* srcq0 = (const ull*)hb0 + ((size_t)(bt * 32 + row)) * 128;
    const ull* srcq1 = (const ull*)hb1 + ((size_t)(bt * 32 + row)) * 128;
    ull* dstq0 = (ull*)hb0 + ((size_t)(bt * 32 + row)) * 128 + hs * 8 + seg;
    ull* dstq1 = (ull*)hb1 + ((size_t)(bt * 32 + row)) * 128 + hs * 8 + seg;

    __syncthreads();   // WfcLDS ready

    for (int s = 0; s < TT; ++s) {
        const ull* srcq = (s & 1) ? srcq1 : srcq0;
        ull*       dstq = (s & 1) ? dstq0 : dstq1;

        // 1. wait: each of lanes 0..15 spins on its own producer slot
        //    (relaxed MALL loads, 64B coalesced per wave-poll, no RMW)
        if (lane < 16) {
            while (__hip_atomic_load(myslots + lane, __ATOMIC_RELAXED,
                                     __HIP_MEMORY_SCOPE_SYSTEM) < s)
                __builtin_amdgcn_s_sleep(2);
        }

        // 2. stage h_s tile [32 x 512] via MALL (sc0 sc1 loads), swizzled LDS
        {
            ull hv[16];
            #pragma unroll
            for (int u = 0; u < 8; ++u) {
                int c = seg * 8 + u;
                hv[2*u]   = __hip_atomic_load((ull*)(srcq + 2*c),     __ATOMIC_RELAXED, __HIP_MEMORY_SCOPE_SYSTEM);
                hv[2*u+1] = __hip_atomic_load((ull*)(srcq + 2*c + 1), __ATOMIC_RELAXED, __HIP_MEMORY_SCOPE_SYSTEM);
            }
            #pragma unroll
            for (int u = 0; u < 8; ++u) {
                int c = seg * 8 + u;
                ull* dst = (ull*)(Alds + row * 512 + ((c ^ r7) << 3));
                dst[0] = hv[2*u];
                dst[1] = hv[2*u+1];
            }
        }
        __syncthreads();

        // 3. FC: step-0 correction (all wgs) and/or y-output (hs==0)
        if (s == 0 || hs == 0) {
            float xacc = 0.f;
            const bf16* arow = Alds + row * 512;
            #pragma unroll
            for (int u = 0; u < 8; ++u) {
                int cc = seg * 8 + u;
                bf16x8 v = *(const bf16x8*)(arow + ((cc ^ r7) << 3));
                const float* wv = WfcLDS + cc * 8;
                #pragma unroll
                for (int e = 0; e < 8; ++e) xacc += (float)v[e] * wv[e];
            }
            xacc += __shfl_xor(xacc, 1);
            xacc += __shfl_xor(xacc, 2);
            xacc += __shfl_xor(xacc, 4);
            xacc += bfcv;
            if (seg == 0) {
                xls[row] = xacc;
                if (hs == 0 && s > 0)
                    out[((size_t)(bt * 32 + row)) * TT + (s - 1)] = xacc;
            }
        }

        // 4. MFMA: [32,512] @ [512, 32 B-rows]; A from swizzled LDS, B from regs
        f32x4 acc[2][2];
        #pragma unroll
        for (int i = 0; i < 2; ++i)
            #pragma unroll
            for (int j = 0; j < 2; ++j) acc[i][j] = (f32x4)0.f;

        #pragma unroll
        for (int kk = 0; kk < 16; ++kk) {
            int ch = ((hi + 4 * kk) ^ swz) << 3;
            bf16x8 a0 = *(const bf16x8*)(Alds + l15 * 512 + ch);
            bf16x8 a1 = *(const bf16x8*)(Alds + (l15 + 16) * 512 + ch);
            acc[0][0] = __builtin_amdgcn_mfma_f32_16x16x32_bf16(a0, breg[0][kk], acc[0][0], 0, 0, 0);
            acc[0][1] = __builtin_amdgcn_mfma_f32_16x16x32_bf16(a0, breg[1][kk], acc[0][1], 0, 0, 0);
            acc[1][0] = __builtin_amdgcn_mfma_f32_16x16x32_bf16(a1, breg[0][kk], acc[1][0], 0, 0, 0);
            acc[1][1] = __builtin_amdgcn_mfma_f32_16x16x32_bf16(a1, breg[1][kk], acc[1][1], 0, 0, 0);
        }

        if (s == 0) __syncthreads();   // xls visible for the correction

        // 5. pointwise cell update; folded weights already include x-feedback
        //    (s==0: subtract x0c*Wih correction since x_0 = 0)
        #pragma unroll
        for (int r = 0; r < 4; ++r) {
            float send0 = lo ? acc[1][0][r] : acc[0][0][r];
            float send1 = lo ? acc[1][1][r] : acc[0][1][r];
            float recv0 = __shfl_xor(send0, 8);
            float recv1 = __shfl_xor(send1, 8);
            float own0  = lo ? acc[0][0][r] : acc[1][0][r];
            float own1  = lo ? acc[0][1][r] : acc[1][1][r];
            int  lrow = mymt * 16 + hi * 4 + r;
            float xc = (s == 0) ? xls[lrow] : 0.f;
            float xi = (lo ? own0 : recv0) + bI - xc * wI;
            float xf = (lo ? recv0 : own0) + bF - xc * wF;
            float xg = (lo ? own1 : recv1) + bG - xc * wG;
            float xo = (lo ? recv1 : own1) + bO - xc * wO;
            float si = sigmoid_fast(xi), sf = sigmoid_fast(xf), so = sigmoid_fast(xo);
            float tg = tanh_fast(xg);
            float cn = sf * creg[r] + si * tg;
            creg[r] = cn;
            hrep[lrow][jcol] = (bf16)(so * tanh_fast(cn));
        }
        __syncthreads();   // hrep ready; Alds reads finished

        // 6. coalesced h store through MALL (sc0 sc1)
        {
            ull val = *(const ull*)&hrep[row][seg * 4];
            __hip_atomic_store(dstq, val, __ATOMIC_RELAXED, __HIP_MEMORY_SCOPE_SYSTEM);
        }
        __syncthreads();   // all waves' stores drained (vmcnt0 at barrier)

        // 7. publish: plain relaxed epoch store (NO RMW, NO wbl2)
        if (tid == 0)
            __hip_atomic_store(myslot, s + 1, __ATOMIC_RELAXED,
                               __HIP_MEMORY_SCOPE_SYSTEM);
    }

    // ---- final output column: y[:, TT-1] = FC(h_TT) ----
    if (hs == 0) {
        if (lane < 16) {
            while (__hip_atomic_load(myslots + lane, __ATOMIC_RELAXED,
                                     __HIP_MEMORY_SCOPE_SYSTEM) < TT)
                __builtin_amdgcn_s_sleep(2);
        }
        const ull* src = (TT & 1) ? srcq1 : srcq0;
        float xacc = 0.f;
        #pragma unroll
        for (int u = 0; u < 8; ++u) {
            int c = seg * 8 + u;
            ull q0 = __hip_atomic_load((ull*)(src + 2*c),     __ATOMIC_RELAXED, __HIP_MEMORY_SCOPE_SYSTEM);
            ull q1 = __hip_atomic_load((ull*)(src + 2*c + 1), __ATOMIC_RELAXED, __HIP_MEMORY_SCOPE_SYSTEM);
            bf16x4v v0 = __builtin_bit_cast(bf16x4v, q0);
            bf16x4v v1 = __builtin_bit_cast(bf16x4v, q1);
            const float* wv = WfcLDS + c * 8;
            #pragma unroll
            for (int e = 0; e < 4; ++e) xacc += (float)v0[e] * wv[e];
            #pragma unroll
            for (int e = 0; e < 4; ++e) xacc += (float)v1[e] * wv[4 + e];
        }
        xacc += __shfl_xor(xacc, 1);
        xacc += __shfl_xor(xacc, 2);
        xacc += __shfl_xor(xacc, 4);
        if (seg == 0)
            out[(size_t)(bt * 32 + row) * TT + (TT - 1)] = xacc + bfcv;
    }
}

extern "C" void kernel_launch(void* const* d_in, const int* in_sizes, int n_in,
                              void* d_out, int out_size, void* d_ws, size_t ws_size,
                              hipStream_t stream) {
    const float* h   = (const float*)d_in[0];
    const float* c   = (const float*)d_in[1];
    const float* Wih = (const float*)d_in[2];
    const float* Whh = (const float*)d_in[3];
    const float* bih = (const float*)d_in[4];
    const float* bhh = (const float*)d_in[5];
    const float* Wfc = (const float*)d_in[6];
    const float* bfc = (const float*)d_in[7];
    float* out = (float*)d_out;

    char* ws = (char*)d_ws;
    bf16*  WcT   = (bf16*)(ws + WT_OFF);
    float* biasC = (float*)(ws + BC_OFF);
    bf16*  hb0   = (bf16*)(ws + H0_OFF);
    bf16*  hb1   = (bf16*)(ws + H1_OFF);
    int*   flags = (int*)(ws + FL_OFF);

    prep_weights<<<2048, 256, 0, stream>>>(Whh, Wih, bih, bhh, Wfc, bfc, WcT, biasC);
    prep_state<<<1024, 256, 0, stream>>>(h, hb0, flags);
    lstm_persist<<<256, 256, 0, stream>>>(WcT, biasC, Wih, Wfc, bfc, c,
                                          hb0, hb1, flags, out);
}